// Round 1
// baseline (416.002 us; speedup 1.0000x reference)
//
#include <hip/hip_runtime.h>

// GATNE-T fused inference — fp32. Shapes: V=500000, T=4, D=32, E=128, A=32, B=8192, S=10.
//
// Two-kernel structure:
//   A) gatne_agg:      node_agg[b][t][d] = mean_s nte[nb[b][t][s]][t][d]
//      barrier-free / LDS-free streaming gather, 8 (b,t) groups per 256-thr block,
//      20 independent 128B row-loads in flight per wave (max MLP).
//   B) gatne_epilogue: attention + proj + l2norm. types/targets via wave-uniform
//      scalar loads; base_emb gather issued at the top to overlap its latency.

constexpr int TT = 4;    // edge types
constexpr int DD = 32;   // edge embedding size
constexpr int EE = 128;  // embedding size
constexpr int AA = 32;   // attention dim
constexpr int SS = 10;   // neighbor samples

// ---------------- Kernel A: aggregation ----------------
// grid = (B*T)/8 blocks of 256 threads; group g = b*T + t.
__global__ __launch_bounds__(256, 8) void gatne_agg(
    const int*   __restrict__ neighbors,   // [B,T,S]
    const float* __restrict__ nte,         // [V,T,D]
    float*       __restrict__ agg)         // [B,T,D]  (workspace)
{
    const int g    = blockIdx.x * 8 + (threadIdx.x >> 5);  // (b*T + t)
    const int lane = threadIdx.x & 31;
    const int t    = g & (TT - 1);

    // neighbor indices: 10 consecutive ints -> compiler vectorizes to dwordx4
    const int* nbp = neighbors + (long long)g * SS;
    int vs[SS];
    #pragma unroll
    for (int s = 0; s < SS; ++s) vs[s] = nbp[s];

    // 10 independent 128B coalesced row gathers
    float acc = 0.f;
    #pragma unroll
    for (int s = 0; s < SS; ++s)
        acc += nte[(long long)vs[s] * (TT * DD) + t * DD + lane];

    agg[(long long)g * DD + lane] = acc * 0.1f;
}

// ---------------- Kernel B: attention + projection + l2norm ----------------
// grid = B blocks of 128 threads (4 groups of 32: t = tid>>5).
__global__ __launch_bounds__(128) void gatne_epilogue(
    const int*   __restrict__ targets,      // [B]
    const int*   __restrict__ types,        // [B]
    const float* __restrict__ agg,          // [B,T,D]
    const float* __restrict__ base_emb,     // [V,E]
    const float* __restrict__ tw,           // [T,D,E]
    const float* __restrict__ tw1,          // [T,D,A]
    const float* __restrict__ tw2,          // [T,A]
    float*       __restrict__ out)          // [B,E]
{
    const int b    = blockIdx.x;
    const int tid  = threadIdx.x;          // 0..127
    const int t    = tid >> 5;             // 0..3
    const int lane = tid & 31;             // 0..31

    __shared__ float s_agg[TT][DD];
    __shared__ float s_scores[TT];
    __shared__ float s_natt[DD];
    __shared__ float s_part[2];
    __shared__ float s_inv;

    // wave-uniform -> scalar loads, no LDS/barrier needed
    const int ty = types[b];
    const int tg = targets[b];

    // prefetch the random base_emb row now; latency overlaps steps 1-4
    const float base_v = base_emb[(long long)tg * EE + tid];

    // ---- 1) stage node_agg (coalesced 128B per group) ----
    const float agg_mine = agg[((long long)b * TT + t) * DD + lane];
    s_agg[t][lane] = agg_mine;
    __syncthreads();

    // ---- 2) u[t][a] = tanh(sum_d agg[t][d] * tw1[ty][d][a]) ; score[t] ----
    float ua = 0.f;
    #pragma unroll
    for (int d = 0; d < DD; ++d)
        ua += s_agg[t][d] * tw1[ty * (DD * AA) + d * AA + lane];
    ua = tanhf(ua);

    float p = ua * tw2[ty * AA + lane];
    #pragma unroll
    for (int m = 16; m >= 1; m >>= 1)
        p += __shfl_xor(p, m, 64);
    if (lane == 0) s_scores[t] = p;
    __syncthreads();

    // ---- 3) softmax over T=4 (redundant per thread; trivial) ----
    const float sc0 = s_scores[0], sc1 = s_scores[1];
    const float sc2 = s_scores[2], sc3 = s_scores[3];
    const float mx  = fmaxf(fmaxf(sc0, sc1), fmaxf(sc2, sc3));
    const float e0 = expf(sc0 - mx), e1 = expf(sc1 - mx);
    const float e2 = expf(sc2 - mx), e3 = expf(sc3 - mx);
    const float inv_sum = 1.f / (e0 + e1 + e2 + e3);

    // ---- 4) node_att[d] = sum_t att[t] * agg[t][d] ----
    if (tid < DD) {
        const float na = (e0 * s_agg[0][tid] + e1 * s_agg[1][tid] +
                          e2 * s_agg[2][tid] + e3 * s_agg[3][tid]) * inv_sum;
        s_natt[tid] = na;
    }
    __syncthreads();

    // ---- 5) proj[e] = sum_d natt[d] * tw[ty][d][e] ; add base; l2 norm ----
    float val = 0.f;
    #pragma unroll
    for (int d = 0; d < DD; ++d)
        val += s_natt[d] * tw[ty * (DD * EE) + d * EE + tid];
    val += base_v;

    float sq = val * val;
    #pragma unroll
    for (int m = 32; m >= 1; m >>= 1)
        sq += __shfl_xor(sq, m, 64);
    if ((tid & 63) == 0) s_part[tid >> 6] = sq;
    __syncthreads();
    if (tid == 0) s_inv = rsqrtf(fmaxf(s_part[0] + s_part[1], 1e-12f));
    __syncthreads();

    out[b * EE + tid] = val * s_inv;
}

extern "C" void kernel_launch(void* const* d_in, const int* in_sizes, int n_in,
                              void* d_out, int out_size, void* d_ws, size_t ws_size,
                              hipStream_t stream) {
    const int*   targets   = (const int*)d_in[0];
    const int*   types     = (const int*)d_in[1];
    const int*   neighbors = (const int*)d_in[2];
    const float* base_emb  = (const float*)d_in[3];
    const float* nte       = (const float*)d_in[4];
    const float* tw        = (const float*)d_in[5];
    const float* tw1       = (const float*)d_in[6];
    const float* tw2       = (const float*)d_in[7];
    float*       out       = (float*)d_out;
    float*       agg       = (float*)d_ws;    // B*T*D*4 = 4 MB  (ws is ~1 GB)

    const int B = in_sizes[0];   // 8192
    (void)n_in; (void)out_size; (void)ws_size;

    // A: (B*T) groups, 8 per 256-thread block
    gatne_agg<<<(B * TT) / 8, 256, 0, stream>>>(neighbors, nte, agg);
    // B: one 128-thread block per batch element
    gatne_epilogue<<<B, 128, 0, stream>>>(targets, types, agg, base_emb,
                                          tw, tw1, tw2, out);
}